// Round 1
// baseline (933.647 us; speedup 1.0000x reference)
//
#include <hip/hip_runtime.h>
#include <hip/hip_bf16.h>
#include <cstdint>
#include <cstddef>

// Problem dims
#define Bn 64
#define Tn 2048
#define Mn 1024   // MEMORY_SIZE (GEMM K)
#define An 512    // ATTN_SIZE
#define Qn 1024   // QUERY_SIZE

#define RT 128    // t-rows per block
#define BK 32     // k-chunk
#define NKC (Mn / BK)   // 32

typedef __attribute__((ext_vector_type(8))) short short8;
typedef __attribute__((ext_vector_type(8))) unsigned short us8;
typedef __attribute__((ext_vector_type(4))) float f32x4;
typedef __attribute__((ext_vector_type(2))) float f32x2;
typedef __attribute__((ext_vector_type(4))) unsigned short us4;

static __device__ __forceinline__ unsigned short f2bf(float f) {
  uint32_t u = __float_as_uint(f);
  u += 0x7fff + ((u >> 16) & 1);   // RNE
  return (unsigned short)(u >> 16);
}

static __device__ __forceinline__ void gl_lds16(const void* g, void* l) {
  __builtin_amdgcn_global_load_lds(
      (const __attribute__((address_space(1))) unsigned int*)g,
      (__attribute__((address_space(3))) unsigned int*)l, 16, 0, 0);
}

// ---------------- prep kernels (unchanged) ----------------
__global__ void zero_kernel(float* __restrict__ ctx, float* __restrict__ Zacc) {
  int i = blockIdx.x * 256 + threadIdx.x;
  if (i < Bn * Mn) ctx[i] = 0.0f;
  else if (i < Bn * Mn + Bn) Zacc[i - Bn * Mn] = 0.0f;
}

__global__ void cvt_wm_kernel(const float* __restrict__ Wm, unsigned short* __restrict__ out) {
  int i = blockIdx.x * 256 + threadIdx.x;
  if (i < An * Mn) out[i] = f2bf(Wm[i]);
}

// w_query[b][a] = sum_m query[b][m] * W_query[a][m]  (fp32 exact, tiny)
__global__ void wq_kernel(const float* __restrict__ query, const float* __restrict__ Wq,
                          float* __restrict__ wqout) {
  __shared__ __align__(16) float qs[Qn];
  const int b = blockIdx.x >> 2;
  const int ag = blockIdx.x & 3;
  const int tid = threadIdx.x;  // 128
  for (int i = tid; i < Qn; i += 128) qs[i] = query[b * Qn + i];
  __syncthreads();
  const int a = ag * 128 + tid;
  const f32x4* w = (const f32x4*)(Wq + (size_t)a * Qn);
  const f32x4* q4 = (const f32x4*)qs;
  float acc = 0.f;
#pragma unroll 8
  for (int m = 0; m < Qn / 4; ++m) {
    f32x4 wv = w[m];
    f32x4 qv = q4[m];
    acc += wv.x * qv.x + wv.y * qv.y + wv.z * qv.z + wv.w * qv.w;
  }
  wqout[b * An + a] = acc;
}

// ---------------- B staging: wave-private slab, pre-swizzled source ----------------
static __device__ __forceinline__ void stage_b(const unsigned short* __restrict__ Wmb,
                                               unsigned short* dst,   // slab base &Bs[p][w*2048]
                                               int ba0, int bj, int k) {
#pragma unroll
  for (int i = 0; i < 4; ++i) {
    int a = ba0 + i * 16;
    int q = (bj - (a >> 1)) & 3;   // logical k-octet stored at physical slot bj
    gl_lds16(Wmb + (size_t)a * Mn + (size_t)k * BK + q * 8, dst + (size_t)i * 512);
  }
}

// ---------------- fused main kernel ----------------
// Block = (b, 128-row t-tile), 512 thr = 8 waves, 1 block/CU (LDS 148.5 KB).
// Deep-pipelined K-loop (T3+T4): raw s_barrier, counted vmcnt (never 0 in loop).
//  - B: wave w writes AND reads only its own 64-a-row slab -> no barrier needed for B;
//       prefetch distance 2 via Bs[4] ring; readiness = own s_waitcnt vmcnt(12).
//  - A: reg-staged fp32->bf16, prefetch distance 2 (av[2]); As[2] ring handed off
//       with ds_write + lgkmcnt(0) + raw s_barrier (the ONLY cross-wave sync).
// Steady state keeps 10-12 vmem ops in flight across every barrier.
__launch_bounds__(512, 2)
__global__ void fused_kernel(const float* __restrict__ mem,
                             const float* __restrict__ wq,
                             const unsigned short* __restrict__ Wmb,
                             const float* __restrict__ Wv,
                             float* __restrict__ out,
                             float* __restrict__ Zacc) {
  __shared__ __align__(16) unsigned short As[2][RT * BK];   // 2 x 8 KB
  __shared__ __align__(16) unsigned short Bs[4][An * BK];   // 4 x 32 KB
  __shared__ float s_score[RT];
  __shared__ float s_e[RT];

  const int tid = threadIdx.x;
  const int b  = blockIdx.x & (Bn - 1);
  const int tt = blockIdx.x >> 6;
  const int t0 = tt * RT;

  const int lane = tid & 63;
  const int w = tid >> 6;        // wave 0..7 -> col slice w*64
  const int l15 = lane & 15;
  const int quad = lane >> 4;

  if (tid < RT) s_score[tid] = 0.f;

  // A staging: thread -> (row = tid>>2, k-octet = tid&3); one 16B bf16 unit per thread
  const int arow = tid >> 2;     // 0..127
  const int ah = tid & 3;        // logical k-octet within 32-k chunk
  const f32x4* ap = (const f32x4*)(mem + ((size_t)(b * Tn + t0 + arow)) * Mn) + ah * 2;
  const int aoff = arow * BK + (((ah + (arow >> 1)) & 3) * 8);   // XOR-swizzled unit

  // B staging map
  const int ba0 = w * 64 + (lane >> 2);
  const int bj = lane & 3;

  // fragment read offsets (ushort idx), swizzle u=(quad+(row>>1))&3
  int aro[8], bro[4];
#pragma unroll
  for (int rt = 0; rt < 8; ++rt) {
    int row = rt * 16 + l15;
    aro[rt] = row * BK + (((quad + (row >> 1)) & 3) * 8);
  }
#pragma unroll
  for (int ct = 0; ct < 4; ++ct) {
    int a = w * 64 + ct * 16 + l15;
    bro[ct] = a * BK + (((quad + (a >> 1)) & 3) * 8);
  }

  f32x4 av[2][2];

  // ---- prologue: issue A(0), B(0), A(1), B(1); write As[0]; barrier ----
  av[0][0] = ap[0];  av[0][1] = ap[1];
  stage_b(Wmb, &Bs[0][w * 2048], ba0, bj, 0);
  av[1][0] = ap[8];  av[1][1] = ap[9];
  stage_b(Wmb, &Bs[1][w * 2048], ba0, bj, 1);
  {
    // compiler inserts counted vmcnt for av[0] (10 younger ops stay in flight)
    us8 o;
    o[0] = (unsigned short)f2bf(av[0][0].x); o[1] = (unsigned short)f2bf(av[0][0].y);
    o[2] = (unsigned short)f2bf(av[0][0].z); o[3] = (unsigned short)f2bf(av[0][0].w);
    o[4] = (unsigned short)f2bf(av[0][1].x); o[5] = (unsigned short)f2bf(av[0][1].y);
    o[6] = (unsigned short)f2bf(av[0][1].z); o[7] = (unsigned short)f2bf(av[0][1].w);
    *(us8*)&As[0][aoff] = o;
  }
  asm volatile("s_waitcnt lgkmcnt(0)" ::: "memory");
  __builtin_amdgcn_sched_barrier(0);
  __builtin_amdgcn_s_barrier();
  __builtin_amdgcn_sched_barrier(0);

  f32x4 acc[8][4] = {};   // [row-tile][col-tile]

  for (int kk = 0; kk < NKC; kk += 4) {
#pragma unroll
    for (int j = 0; j < 4; ++j) {      // phase j: kc = kk + j; all ring indices static
      const int kc = kk + j;
      int k2 = kc + 2; if (k2 > NKC - 1) k2 = NKC - 1;   // tail: harmless junk prefetch

      // issue A(kc+2) -> av[j&1] (regs), then B(kc+2) -> own slab of Bs[(j+2)&3]
      av[j & 1][0] = ap[(size_t)k2 * 8];
      av[j & 1][1] = ap[(size_t)k2 * 8 + 1];
      stage_b(Wmb, &Bs[(j + 2) & 3][w * 2048], ba0, bj, k2);

      // own B(kc) slab landed: exactly 12 younger vmem ops (2 iters x (2 A + 4 B))
      asm volatile("s_waitcnt vmcnt(12)" ::: "memory");

      short8 bfv[4];
#pragma unroll
      for (int i = 0; i < 4; ++i) bfv[i] = *(const short8*)&Bs[j][bro[i]];
#pragma unroll
      for (int rt = 0; rt < 8; ++rt) {
        short8 afr = *(const short8*)&As[j & 1][aro[rt]];
#pragma unroll
        for (int ct = 0; ct < 4; ++ct)
          acc[rt][ct] = __builtin_amdgcn_mfma_f32_16x16x32_bf16(afr, bfv[ct], acc[rt][ct], 0, 0, 0);
      }

      // write A(kc+1) from av[(j+1)&1] (loaded last iter; compiler emits vmcnt(10))
      {
        f32x4 a0 = av[(j + 1) & 1][0], a1 = av[(j + 1) & 1][1];
        us8 o;
        o[0] = (unsigned short)f2bf(a0.x); o[1] = (unsigned short)f2bf(a0.y);
        o[2] = (unsigned short)f2bf(a0.z); o[3] = (unsigned short)f2bf(a0.w);
        o[4] = (unsigned short)f2bf(a1.x); o[5] = (unsigned short)f2bf(a1.y);
        o[6] = (unsigned short)f2bf(a1.z); o[7] = (unsigned short)f2bf(a1.w);
        *(us8*)&As[(j + 1) & 1][aoff] = o;
      }
      asm volatile("s_waitcnt lgkmcnt(0)" ::: "memory");
      __builtin_amdgcn_sched_barrier(0);
      __builtin_amdgcn_s_barrier();     // raw barrier: vmem prefetches stay in flight
      __builtin_amdgcn_sched_barrier(0);
    }
  }

  // ---- phase 2: scores s_t = sum_a v_a * tanh(wq_a + wm[t][a]) ----
  // C/D layout: col = lane&15 (a), row = quad*4 + reg (t)
  const float* wqb = wq + b * An;
  {
    float rs[8][4];
#pragma unroll
    for (int rt = 0; rt < 8; ++rt)
#pragma unroll
      for (int g = 0; g < 4; ++g) rs[rt][g] = 0.f;

#pragma unroll
    for (int ct = 0; ct < 4; ++ct) {
      const int a = w * 64 + ct * 16 + l15;
      const float wqa = wqb[a];
      const float va = Wv[a];
#pragma unroll
      for (int rt = 0; rt < 8; ++rt) {
#pragma unroll
        for (int g = 0; g < 4; ++g) {
          float x = wqa + acc[rt][ct][g];
          float ez = __expf(2.0f * x);
          float th = 1.0f - 2.0f * __builtin_amdgcn_rcpf(ez + 1.0f);
          rs[rt][g] += va * th;
        }
      }
    }
#pragma unroll
    for (int rt = 0; rt < 8; ++rt) {
#pragma unroll
      for (int g = 0; g < 4; ++g) {
        float v = rs[rt][g];
        v += __shfl_xor(v, 1);
        v += __shfl_xor(v, 2);
        v += __shfl_xor(v, 4);
        v += __shfl_xor(v, 8);
        if (l15 == 0) atomicAdd(&s_score[rt * 16 + quad * 4 + g], v);
      }
    }
  }
  __syncthreads();   // also drains the tail's junk prefetches

  // ---- e_t, Z partial; write unnormalized alpha ----
  if (tid < RT) {    // 2 full waves
    float e = __expf(s_score[tid]);   // |s| <= 22.6, fp32-safe without max-sub
    s_e[tid] = e;
    out[(size_t)b * Tn + t0 + tid] = e;
    float z = e;
    z += __shfl_xor(z, 1);
    z += __shfl_xor(z, 2);
    z += __shfl_xor(z, 4);
    z += __shfl_xor(z, 8);
    z += __shfl_xor(z, 16);
    z += __shfl_xor(z, 32);
    if (lane == 0) atomicAdd(&Zacc[b], z);
  }
  __syncthreads();

  // ---- phase 3: context partial, re-read memory (fp32, L2/L3-hot) ----
  {
    const float* mrow = mem + ((size_t)(b * Tn + t0)) * Mn + 2 * tid;
    float c0 = 0.f, c1 = 0.f;
#pragma unroll 16
    for (int r = 0; r < RT; ++r) {
      f32x2 v = *(const f32x2*)(mrow + (size_t)r * Mn);
      float e = s_e[r];
      c0 += e * v.x;
      c1 += e * v.y;
    }
    float* ctx = out + Bn * Tn + (size_t)b * Mn + 2 * tid;
    atomicAdd(&ctx[0], c0);
    atomicAdd(&ctx[1], c1);
  }
}

// ---------------- finalize: divide by Z ----------------
__global__ void finalize_kernel(float* __restrict__ out, const float* __restrict__ Zacc) {
  int i = blockIdx.x * 256 + threadIdx.x;
  if (i < Bn * Tn) {
    int b = i >> 11;           // / Tn
    out[i] /= Zacc[b];
  } else if (i < Bn * Tn + Bn * Mn) {
    int j = i - Bn * Tn;
    int b = j >> 10;           // / Mn
    out[i] /= Zacc[b];
  }
}

extern "C" void kernel_launch(void* const* d_in, const int* in_sizes, int n_in,
                              void* d_out, int out_size, void* d_ws, size_t ws_size,
                              hipStream_t stream) {
  const float* query    = (const float*)d_in[0];  // [64,1024]
  const float* memory   = (const float*)d_in[1];  // [64,2048,1024]
  const float* W_query  = (const float*)d_in[2];  // [512,1024]
  const float* W_memory = (const float*)d_in[3];  // [512,1024]
  const float* W_v      = (const float*)d_in[4];  // [1,512]
  float* out = (float*)d_out;                     // alpha[64,2048] ++ context[64,1024]

  // ws: wq (128 KB) | Wm bf16 (1 MB) | Zacc (256 B)
  float* wq = (float*)d_ws;
  unsigned short* Wmb = (unsigned short*)((char*)d_ws + (size_t)Bn * An * 4);
  float* Zacc = (float*)((char*)d_ws + (size_t)Bn * An * 4 + (size_t)An * Mn * 2);

  zero_kernel<<<(Bn * Mn + Bn + 255) / 256, 256, 0, stream>>>(out + Bn * Tn, Zacc);
  cvt_wm_kernel<<<(An * Mn + 255) / 256, 256, 0, stream>>>(W_memory, Wmb);
  wq_kernel<<<Bn * 4, 128, 0, stream>>>(query, W_query, wq);
  fused_kernel<<<Bn * (Tn / RT), 512, 0, stream>>>(memory, wq, Wmb, W_v, out, Zacc);
  finalize_kernel<<<(Bn * Tn + Bn * Mn + 255) / 256, 256, 0, stream>>>(out, Zacc);
}

// Round 2
// 880.004 us; speedup vs baseline: 1.0610x; 1.0610x over previous
//
#include <hip/hip_runtime.h>
#include <hip/hip_bf16.h>
#include <cstdint>
#include <cstddef>

// Problem dims
#define Bn 64
#define Tn 2048
#define Mn 1024   // MEMORY_SIZE (GEMM K)
#define An 512    // ATTN_SIZE
#define Qn 1024   // QUERY_SIZE

#define RT 64     // t-rows per block
#define BK 32     // k-chunk
#define NKC (Mn / BK)   // 32

typedef __attribute__((ext_vector_type(8))) short short8;
typedef __attribute__((ext_vector_type(8))) unsigned short us8;
typedef __attribute__((ext_vector_type(4))) float f32x4;
typedef __attribute__((ext_vector_type(2))) float f32x2;
typedef __attribute__((ext_vector_type(4))) unsigned short us4;

static __device__ __forceinline__ unsigned short f2bf(float f) {
  uint32_t u = __float_as_uint(f);
  u += 0x7fff + ((u >> 16) & 1);   // RNE
  return (unsigned short)(u >> 16);
}

// ---------------- prep kernels ----------------
__global__ void zero_kernel(float* __restrict__ ctx, float* __restrict__ Zacc) {
  int i = blockIdx.x * 256 + threadIdx.x;
  if (i < Bn * Mn) ctx[i] = 0.0f;
  else if (i < Bn * Mn + Bn) Zacc[i - Bn * Mn] = 0.0f;
}

// Repack W_memory (fp32 [512][1024]) into MFMA-fragment-ordered bf16 so the
// fused kernel's B loads are fully lane-contiguous:
//   chunk c = (kc*32 + ab)*64 + lane   holds short8 with
//   element e = bf16( Wm[ab*16 + (lane&15)][kc*32 + (lane>>4)*8 + e] )
__global__ void cvt_wm_kernel(const float* __restrict__ Wm, unsigned short* __restrict__ out) {
  int t = blockIdx.x * 256 + threadIdx.x;     // 65536 total
  if (t >= (An * Mn) / 8) return;
  int kc  = t >> 11;
  int ab  = (t >> 6) & 31;
  int lane = t & 63;
  int row = ab * 16 + (lane & 15);
  int col = kc * 32 + (lane >> 4) * 8;
  const float* src = Wm + (size_t)row * Mn + col;
  us8 o;
#pragma unroll
  for (int e = 0; e < 8; ++e) o[e] = f2bf(src[e]);
  *(us8*)(out + (size_t)t * 8) = o;
}

// w_query[b][a] = sum_m query[b][m] * W_query[a][m]  (fp32 exact, tiny)
__global__ void wq_kernel(const float* __restrict__ query, const float* __restrict__ Wq,
                          float* __restrict__ wqout) {
  __shared__ __align__(16) float qs[Qn];
  const int b = blockIdx.x >> 2;
  const int ag = blockIdx.x & 3;
  const int tid = threadIdx.x;  // 128
  for (int i = tid; i < Qn; i += 128) qs[i] = query[b * Qn + i];
  __syncthreads();
  const int a = ag * 128 + tid;
  const f32x4* w = (const f32x4*)(Wq + (size_t)a * Qn);
  const f32x4* q4 = (const f32x4*)qs;
  float acc = 0.f;
#pragma unroll 8
  for (int m = 0; m < Qn / 4; ++m) {
    f32x4 wv = w[m];
    f32x4 qv = q4[m];
    acc += wv.x * qv.x + wv.y * qv.y + wv.z * qv.z + wv.w * qv.w;
  }
  wqout[b * An + a] = acc;
}

// ---------------- fused main kernel ----------------
// Block = (b, 64-row t-tile), 512 thr = 8 waves, ~2 blocks/CU (LDS only 8.7 KB).
// B (Wmb repacked) is L2-resident and per-element single-use -> loaded DIRECT to
// registers, fully coalesced (no LDS staging, no gl_lds scatter). Only the shared
// A tile lives in LDS (2 x 4 KB ring, depth-2 register prefetch of the HBM stream).
// Barrier = lgkmcnt(0) + raw s_barrier: no vmem drain needed since all vmem ops
// target private registers -> the A prefetch stays in flight across barriers.
__launch_bounds__(512, 4)
__global__ void fused_kernel(const float* __restrict__ mem,
                             const float* __restrict__ wq,
                             const unsigned short* __restrict__ Wmb,
                             const float* __restrict__ Wv,
                             float* __restrict__ out,
                             float* __restrict__ Zacc) {
  __shared__ __align__(16) unsigned short As[2][RT * BK];   // 2 x 4 KB
  __shared__ float s_score[RT];
  __shared__ float s_e[RT];

  const int tid = threadIdx.x;
  const int b  = blockIdx.x & (Bn - 1);
  const int tt = blockIdx.x >> 6;
  const int t0 = tt * RT;

  const int lane = tid & 63;
  const int w = tid >> 6;        // wave 0..7 -> col slice w*64
  const int l15 = lane & 15;
  const int quad = lane >> 4;

  if (tid < RT) s_score[tid] = 0.f;

  // A staging: thread -> (row=tid>>3, 4-float k-group h=tid&7); contiguous 128B/row
  const int arow = tid >> 3;
  const int ah = tid & 7;
  const float* asrc = mem + ((size_t)(b * Tn + t0 + arow)) * Mn + ah * 4;
  const int au = ((ah >> 1) + (arow >> 1)) & 3;              // physical 16B unit
  const int aoff = arow * BK + au * 8 + (ah & 1) * 4;        // ushort index

  // A fragment read offsets (ushort idx), swizzle u=(quad+(row>>1))&3
  int aro[4];
#pragma unroll
  for (int rt = 0; rt < 4; ++rt) {
    int row = rt * 16 + l15;
    aro[rt] = row * BK + (((quad + (row >> 1)) & 3) * 8);
  }

  // B direct-load base (chunk index into repacked Wmb)
  const short8* bp = (const short8*)Wmb;
  const int bbase = (w * 4) * 64 + lane;    // + kc*2048 + ct*64 per fragment

  // ---- prologue: A depth-2 reg prefetch, write As[0] ----
  f32x4 av[2];
  av[0] = *(const f32x4*)asrc;
  av[1] = *(const f32x4*)(asrc + BK);
  {
    us4 o; o.x = f2bf(av[0].x); o.y = f2bf(av[0].y); o.z = f2bf(av[0].z); o.w = f2bf(av[0].w);
    *(us4*)&As[0][aoff] = o;
  }
  asm volatile("s_waitcnt lgkmcnt(0)" ::: "memory");
  __builtin_amdgcn_sched_barrier(0);
  __builtin_amdgcn_s_barrier();
  __builtin_amdgcn_sched_barrier(0);

  f32x4 acc[4][4] = {};   // [row-tile][col-tile]

#pragma unroll 2
  for (int kc = 0; kc < NKC; ++kc) {
    // A prefetch (chunk kc+2) into the reg slot whose data is already in LDS
    if (kc + 2 < NKC) av[kc & 1] = *(const f32x4*)(asrc + (size_t)(kc + 2) * BK);

    // B fragments: 4 coalesced 16B loads from L2-resident repacked Wmb
    short8 bfv[4];
#pragma unroll
    for (int ct = 0; ct < 4; ++ct) bfv[ct] = bp[bbase + kc * 2048 + ct * 64];

    short8 af[4];
#pragma unroll
    for (int i = 0; i < 4; ++i) af[i] = *(const short8*)&As[kc & 1][aro[i]];

#pragma unroll
    for (int rt = 0; rt < 4; ++rt)
#pragma unroll
      for (int ct = 0; ct < 4; ++ct)
        acc[rt][ct] = __builtin_amdgcn_mfma_f32_16x16x32_bf16(af[rt], bfv[ct], acc[rt][ct], 0, 0, 0);

    // hand chunk kc+1 (loaded last iter) to the other LDS buffer
    if (kc + 1 < NKC) {
      f32x4 a = av[(kc + 1) & 1];
      us4 o; o.x = f2bf(a.x); o.y = f2bf(a.y); o.z = f2bf(a.z); o.w = f2bf(a.w);
      *(us4*)&As[(kc + 1) & 1][aoff] = o;
    }
    asm volatile("s_waitcnt lgkmcnt(0)" ::: "memory");
    __builtin_amdgcn_sched_barrier(0);
    __builtin_amdgcn_s_barrier();     // raw: A prefetch stays in flight
    __builtin_amdgcn_sched_barrier(0);
  }

  // ---- phase 2: scores s_t = sum_a v_a * tanh(wq_a + wm[t][a]) ----
  // C/D layout: col = lane&15 (a), row = quad*4 + reg (t)
  const float* wqb = wq + b * An;
  {
    float rs[4][4];
#pragma unroll
    for (int rt = 0; rt < 4; ++rt)
#pragma unroll
      for (int g = 0; g < 4; ++g) rs[rt][g] = 0.f;

#pragma unroll
    for (int ct = 0; ct < 4; ++ct) {
      const int a = w * 64 + ct * 16 + l15;
      const float wqa = wqb[a];
      const float va = Wv[a];
#pragma unroll
      for (int rt = 0; rt < 4; ++rt) {
#pragma unroll
        for (int g = 0; g < 4; ++g) {
          float x = wqa + acc[rt][ct][g];
          float ez = __expf(2.0f * x);
          float th = 1.0f - 2.0f * __builtin_amdgcn_rcpf(ez + 1.0f);
          rs[rt][g] += va * th;
        }
      }
    }
#pragma unroll
    for (int rt = 0; rt < 4; ++rt) {
#pragma unroll
      for (int g = 0; g < 4; ++g) {
        float v = rs[rt][g];
        v += __shfl_xor(v, 1);
        v += __shfl_xor(v, 2);
        v += __shfl_xor(v, 4);
        v += __shfl_xor(v, 8);
        if (l15 == 0) atomicAdd(&s_score[rt * 16 + quad * 4 + g], v);
      }
    }
  }
  __syncthreads();

  // ---- e_t, Z partial; write unnormalized alpha ----
  if (tid < RT) {
    float e = __expf(s_score[tid]);   // |s| <= 22.6, fp32-safe without max-sub
    s_e[tid] = e;
    out[(size_t)b * Tn + t0 + tid] = e;
    float z = e;
    z += __shfl_xor(z, 1);
    z += __shfl_xor(z, 2);
    z += __shfl_xor(z, 4);
    z += __shfl_xor(z, 8);
    z += __shfl_xor(z, 16);
    z += __shfl_xor(z, 32);
    if (lane == 0) atomicAdd(&Zacc[b], z);
  }
  __syncthreads();

  // ---- phase 3: context partial, re-read memory (fp32, L2/L3-hot) ----
  {
    const float* mrow = mem + ((size_t)(b * Tn + t0)) * Mn + 2 * tid;
    float c0 = 0.f, c1 = 0.f;
#pragma unroll 8
    for (int r = 0; r < RT; ++r) {
      f32x2 v = *(const f32x2*)(mrow + (size_t)r * Mn);
      float e = s_e[r];
      c0 += e * v.x;
      c1 += e * v.y;
    }
    float* ctx = out + Bn * Tn + (size_t)b * Mn + 2 * tid;
    atomicAdd(&ctx[0], c0);
    atomicAdd(&ctx[1], c1);
  }
}

// ---------------- finalize: divide by Z ----------------
__global__ void finalize_kernel(float* __restrict__ out, const float* __restrict__ Zacc) {
  int i = blockIdx.x * 256 + threadIdx.x;
  if (i < Bn * Tn) {
    int b = i >> 11;           // / Tn
    out[i] /= Zacc[b];
  } else if (i < Bn * Tn + Bn * Mn) {
    int j = i - Bn * Tn;
    int b = j >> 10;           // / Mn
    out[i] /= Zacc[b];
  }
}

extern "C" void kernel_launch(void* const* d_in, const int* in_sizes, int n_in,
                              void* d_out, int out_size, void* d_ws, size_t ws_size,
                              hipStream_t stream) {
  const float* query    = (const float*)d_in[0];  // [64,1024]
  const float* memory   = (const float*)d_in[1];  // [64,2048,1024]
  const float* W_query  = (const float*)d_in[2];  // [512,1024]
  const float* W_memory = (const float*)d_in[3];  // [512,1024]
  const float* W_v      = (const float*)d_in[4];  // [1,512]
  float* out = (float*)d_out;                     // alpha[64,2048] ++ context[64,1024]

  // ws: wq (128 KB) | Wm bf16 repacked (1 MB) | Zacc (256 B)
  float* wq = (float*)d_ws;
  unsigned short* Wmb = (unsigned short*)((char*)d_ws + (size_t)Bn * An * 4);
  float* Zacc = (float*)((char*)d_ws + (size_t)Bn * An * 4 + (size_t)An * Mn * 2);

  zero_kernel<<<(Bn * Mn + Bn + 255) / 256, 256, 0, stream>>>(out + Bn * Tn, Zacc);
  cvt_wm_kernel<<<(An * Mn / 8 + 255) / 256, 256, 0, stream>>>(W_memory, Wmb);
  wq_kernel<<<Bn * 4, 128, 0, stream>>>(query, W_query, wq);
  fused_kernel<<<Bn * (Tn / RT), 512, 0, stream>>>(memory, wq, Wmb, W_v, out, Zacc);
  finalize_kernel<<<(Bn * Tn + Bn * Mn + 255) / 256, 256, 0, stream>>>(out, Zacc);
}